// Round 1
// baseline (693.606 us; speedup 1.0000x reference)
//
#include <hip/hip_runtime.h>
#include <math.h>

#define BLK 256
#define TT  4096   // T0 = min(16^3, 2^19) = 4096 for every level

// Dense layer accumulate: acc[OD] = B + xrow(swizzled)^T W.
// Weight/bias indices are wave-uniform -> scalar loads (s_load) + v_fmac v,s,v.
// acc is compile-time indexed -> stays in VGPRs.
template<int ID, int OD>
__device__ __forceinline__ void dense_acc(const float* xrow, int swz,
                                          const float* __restrict__ W,
                                          const float* __restrict__ B,
                                          float* acc) {
  #pragma unroll
  for (int j = 0; j < OD; ++j) acc[j] = B[j];
  #pragma unroll 2
  for (int k = 0; k < ID; ++k) {
    float x = xrow[k ^ swz];            // LDS, 2-way bank alias max (free)
    #pragma unroll
    for (int j = 0; j < OD; ++j) acc[j] = fmaf(x, W[k * OD + j], acc[j]);
  }
}

__global__ __launch_bounds__(BLK)
void ngp_fused(const float* __restrict__ pos,
               const float* __restrict__ dirs,
               const float* __restrict__ emb,
               const float* __restrict__ gw0, const float* __restrict__ gb0,
               const float* __restrict__ gw1, const float* __restrict__ gb1,
               const float* __restrict__ dw,  const float* __restrict__ db,
               const float* __restrict__ cw0, const float* __restrict__ cb0,
               const float* __restrict__ cw1, const float* __restrict__ cb1,
               const float* __restrict__ cw2, const float* __restrict__ cb2,
               const float* __restrict__ rw,  const float* __restrict__ rb,
               float* __restrict__ outd, float* __restrict__ outrgb, int N)
{
  // 64 KB exactly: encode phase = 32KB level table (first half);
  // MLP phase = per-thread 64-f32 activation row, XOR-swizzled.
  __shared__ float smem[BLK * 64];

  const int tid = threadIdx.x;
  const int idx = blockIdx.x * BLK + tid;
  const bool act = idx < N;
  const int ic = act ? idx : (N - 1);

  // pn = positions / BOUND (BOUND = 2)
  const float pnx = pos[3 * ic + 0] * 0.5f;
  const float pny = pos[3 * ic + 1] * 0.5f;
  const float pnz = pos[3 * ic + 2] * 0.5f;

  float enc[32];
  float2* tab  = (float2*)smem;
  float4* tab4 = (float4*)smem;

  #pragma unroll
  for (int li = 0; li < 16; ++li) {
    // ---- stage this level's 32KB table into LDS (coalesced float4) ----
    const float4* src4 = (const float4*)(emb + li * (TT * 2));
    #pragma unroll
    for (int j = 0; j < (TT * 2 / 4) / BLK; ++j)       // 8 iters
      tab4[tid + j * BLK] = src4[tid + j * BLK];
    __syncthreads();

    const int   res = 16 << li;                        // RES[li] = ceil(16*2^li)
    const float rm1 = (float)(res - 1);
    // scaled = (pn + 1) * 0.5 * (res-1), matching reference op order
    float sx = (pnx + 1.0f) * 0.5f * rm1;
    float sy = (pny + 1.0f) * 0.5f * rm1;
    float sz = (pnz + 1.0f) * 0.5f * rm1;
    float fx = floorf(sx), fy = floorf(sy), fz = floorf(sz);
    float wx = sx - fx,    wy = sy - fy,    wz = sz - fz;
    int ix = (int)fx, iy = (int)fy, iz = (int)fz;
    int x0 = min(max(ix, 0),     res - 1), x1 = min(max(ix + 1, 0), res - 1);
    int y0 = min(max(iy, 0),     res - 1), y1 = min(max(iy + 1, 0), res - 1);
    int z0 = min(max(iz, 0),     res - 1), z1 = min(max(iz + 1, 0), res - 1);
    // hash = (x*1 ^ y*2481 ^ z*1941) & 4095  (PRIMES pre-mod'ed by T0; &4095
    // == Python floor-mod for any wrapped int32)
    unsigned a0 = (unsigned)x0,          a1 = (unsigned)x1;
    unsigned b0 = (unsigned)y0 * 2481u,  b1 = (unsigned)y1 * 2481u;
    unsigned d0 = (unsigned)z0 * 1941u,  d1 = (unsigned)z1 * 1941u;
    // OFFS order: (dx,dy,dz) with dz fastest: f0=(000) f1=(001) f2=(010)
    // f3=(011) f4=(100) f5=(101) f6=(110) f7=(111)
    float2 f0 = tab[(a0 ^ b0 ^ d0) & 4095u];
    float2 f1 = tab[(a0 ^ b0 ^ d1) & 4095u];
    float2 f2 = tab[(a0 ^ b1 ^ d0) & 4095u];
    float2 f3 = tab[(a0 ^ b1 ^ d1) & 4095u];
    float2 f4 = tab[(a1 ^ b0 ^ d0) & 4095u];
    float2 f5 = tab[(a1 ^ b0 ^ d1) & 4095u];
    float2 f6 = tab[(a1 ^ b1 ^ d0) & 4095u];
    float2 f7 = tab[(a1 ^ b1 ^ d1) & 4095u];
    // Reference blends literally: wx pairs (f0,f1)(f2,f3)(f4,f5)(f6,f7),
    // then wy, then wz — replicate exactly (do NOT "fix" axis order).
    float omx = 1.0f - wx, omy = 1.0f - wy, omz = 1.0f - wz;
    float c00x = f0.x * omx + f1.x * wx, c00y = f0.y * omx + f1.y * wx;
    float c01x = f2.x * omx + f3.x * wx, c01y = f2.y * omx + f3.y * wx;
    float c10x = f4.x * omx + f5.x * wx, c10y = f4.y * omx + f5.y * wx;
    float c11x = f6.x * omx + f7.x * wx, c11y = f6.y * omx + f7.y * wx;
    float e0x = c00x * omy + c01x * wy,  e0y = c00y * omy + c01y * wy;
    float e1x = c10x * omy + c11x * wy,  e1y = c10y * omy + c11y * wy;
    enc[2 * li + 0] = e0x * omz + e1x * wz;
    enc[2 * li + 1] = e0y * omz + e1y * wz;
    __syncthreads();   // before next level overwrites the table
  }

  // ---- MLP phase: activations in LDS row (XOR swizzle -> 2-way max) ----
  float* xrow = smem + tid * 64;
  const int swz = tid & 31;

  #pragma unroll
  for (int k = 0; k < 32; ++k) xrow[k ^ swz] = enc[k];

  { float acc[64];
    dense_acc<32, 64>(xrow, swz, gw0, gb0, acc);
    #pragma unroll
    for (int j = 0; j < 64; ++j) xrow[j ^ swz] = fmaxf(acc[j], 0.0f); }
  { float acc[64];
    dense_acc<64, 64>(xrow, swz, gw1, gb1, acc);
    #pragma unroll
    for (int j = 0; j < 64; ++j) xrow[j ^ swz] = fmaxf(acc[j], 0.0f); }

  float g[16];
  dense_acc<64, 16>(xrow, swz, dw, db, g);
  const float density = expf(g[0] - 1.0f);

  // c = concat(geo_feat = g[1:16], sh16(dirs))  -> 31 inputs
  #pragma unroll
  for (int j = 1; j < 16; ++j) xrow[(j - 1) ^ swz] = g[j];

  float ddx = dirs[3 * ic + 0], ddy = dirs[3 * ic + 1], ddz = dirs[3 * ic + 2];
  float nrm = fmaxf(sqrtf(ddx * ddx + ddy * ddy + ddz * ddz), 1e-12f);
  float x = ddx / nrm, y = ddy / nrm, z = ddz / nrm;
  float xx = x * x, yy = y * y, zz = z * z;
  float xy = x * y, yz = y * z, xz = x * z;
  xrow[15 ^ swz] = 0.28209479177387814f;
  xrow[16 ^ swz] = -0.48860251190291987f * y;
  xrow[17 ^ swz] =  0.48860251190291987f * z;
  xrow[18 ^ swz] = -0.48860251190291987f * x;
  xrow[19 ^ swz] =  1.0925484305920792f * xy;
  xrow[20 ^ swz] = -1.0925484305920792f * yz;
  xrow[21 ^ swz] =  0.31539156525252005f * (2.0f * zz - xx - yy);
  xrow[22 ^ swz] = -1.0925484305920792f * xz;
  xrow[23 ^ swz] =  0.5462742152960396f * (xx - yy);
  xrow[24 ^ swz] = -0.5900435899266435f * y * (3.0f * xx - yy);
  xrow[25 ^ swz] =  2.890611442640554f * xy * z;
  xrow[26 ^ swz] = -0.4570457994644658f * y * (4.0f * zz - xx - yy);
  xrow[27 ^ swz] =  0.3731763325901154f * z * (2.0f * zz - 3.0f * xx - 3.0f * yy);
  xrow[28 ^ swz] = -0.4570457994644658f * x * (4.0f * zz - xx - yy);
  xrow[29 ^ swz] =  1.445305721320277f * z * (xx - yy);
  xrow[30 ^ swz] = -0.5900435899266435f * x * (xx - 3.0f * yy);

  { float acc[64];
    dense_acc<31, 64>(xrow, swz, cw0, cb0, acc);
    #pragma unroll
    for (int j = 0; j < 64; ++j) xrow[j ^ swz] = fmaxf(acc[j], 0.0f); }
  { float acc[64];
    dense_acc<64, 64>(xrow, swz, cw1, cb1, acc);
    #pragma unroll
    for (int j = 0; j < 64; ++j) xrow[j ^ swz] = acc[j]; }   // no relu
  { float acc[64];
    dense_acc<64, 64>(xrow, swz, cw2, cb2, acc);
    #pragma unroll
    for (int j = 0; j < 64; ++j) xrow[j ^ swz] = acc[j]; }   // no relu

  float r[3];
  dense_acc<64, 3>(xrow, swz, rw, rb, r);

  if (act) {
    outd[idx] = density;
    #pragma unroll
    for (int j = 0; j < 3; ++j)
      outrgb[3 * idx + j] = 1.0f / (1.0f + expf(-r[j]));
  }
}

extern "C" void kernel_launch(void* const* d_in, const int* in_sizes, int n_in,
                              void* d_out, int out_size, void* d_ws, size_t ws_size,
                              hipStream_t stream) {
  const float* pos  = (const float*)d_in[0];
  const float* dirs = (const float*)d_in[1];
  const float* emb  = (const float*)d_in[2];
  const float* gw0  = (const float*)d_in[3];
  const float* gb0  = (const float*)d_in[4];
  const float* gw1  = (const float*)d_in[5];
  const float* gb1  = (const float*)d_in[6];
  const float* dw   = (const float*)d_in[7];
  const float* db   = (const float*)d_in[8];
  const float* cw0  = (const float*)d_in[9];
  const float* cb0  = (const float*)d_in[10];
  const float* cw1  = (const float*)d_in[11];
  const float* cb1  = (const float*)d_in[12];
  const float* cw2  = (const float*)d_in[13];
  const float* cb2  = (const float*)d_in[14];
  const float* rw   = (const float*)d_in[15];
  const float* rb   = (const float*)d_in[16];

  const int N = in_sizes[0] / 3;
  float* outd   = (float*)d_out;        // density: N
  float* outrgb = outd + N;             // rgb: 3N

  const int grid = (N + BLK - 1) / BLK;
  hipLaunchKernelGGL(ngp_fused, dim3(grid), dim3(BLK), 0, stream,
                     pos, dirs, emb, gw0, gb0, gw1, gb1, dw, db,
                     cw0, cb0, cw1, cb1, cw2, cb2, rw, rb,
                     outd, outrgb, N);
}

// Round 9
// 420.808 us; speedup vs baseline: 1.6483x; 1.6483x over previous
//
#include <hip/hip_runtime.h>
#include <math.h>

#define BLK 256
#define TT  4096   // T0 = min(16^3, 2^19) = 4096 for every level

typedef short bf16x8 __attribute__((ext_vector_type(8)));
typedef float f32x4  __attribute__((ext_vector_type(4)));

__device__ __forceinline__ unsigned short f2bf(float f) {
  unsigned u = __builtin_bit_cast(unsigned, f);
  return (unsigned short)((u + 0x7FFFu + ((u >> 16) & 1u)) >> 16);
}
__device__ __forceinline__ unsigned pk(float a, float b) {
  return (unsigned)f2bf(a) | ((unsigned)f2bf(b) << 16);
}
__device__ __forceinline__ f32x4 mfma16(bf16x8 a, bf16x8 b, f32x4 c) {
  return __builtin_amdgcn_mfma_f32_16x16x32_bf16(a, b, c, 0, 0, 0);
}

// ---- B-fragment builders: pure cross-lane (no LDS) -------------------------
// MFMA frag conventions (m89-verified D; A/B k-permutation cancels when A and
// B use the same convention): lane (q,p): A[row=p][k=32kt+8q+j];
// B[k=32kt+8q+j][col=p]; D[row=4q+r][col=p].

// B from per-point packed pairs ep[16] (32 features, owner lane = src):
// consumer (q,p) needs pair (4q+w) of point src.
__device__ __forceinline__ bf16x8 bfrag_pt(const unsigned (&ep)[16], int src, int q) {
  bf16x8 b;
  #pragma unroll
  for (int w = 0; w < 4; ++w) {
    int v0 = __shfl((int)ep[w],      src);
    int v1 = __shfl((int)ep[4 + w],  src);
    int v2 = __shfl((int)ep[8 + w],  src);
    int v3 = __shfl((int)ep[12 + w], src);
    int lo = (q & 1) ? v1 : v0;
    int hi = (q & 1) ? v3 : v2;
    unsigned word = (unsigned)((q & 2) ? hi : lo);
    b[2 * w]     = (short)(word & 0xFFFFu);
    b[2 * w + 1] = (short)(word >> 16);
  }
  return b;
}

// B (kt half) from previous 64-wide layer's packed D: unt[mt][half] where
// unt[mt][h] = (f = 16mt+4q_src+2h, +1). Feature f0 = 32kt+8q+2w lives at
// mt = 2kt+(q>>1), q_src = (2q+(w>>1))&3, half = w&1.
template<int KT_>
__device__ __forceinline__ bf16x8 bfrag_u(const unsigned (&unt)[4][2], int q, int p) {
  bf16x8 b;
  #pragma unroll
  for (int w = 0; w < 4; ++w) {
    int src = (((2 * q + (w >> 1)) & 3) << 4) + p;
    int v0 = __shfl((int)unt[2 * KT_][w & 1],     src);
    int v1 = __shfl((int)unt[2 * KT_ + 1][w & 1], src);
    unsigned word = (unsigned)((q >> 1) ? v1 : v0);
    b[2 * w]     = (short)(word & 0xFFFFu);
    b[2 * w + 1] = (short)(word >> 16);
  }
  return b;
}

// B for the 31-concat (g[0..15] from D-layout g2nt, sh[0..15] from owner lane):
// f<16 (q<2): g2nt[w&1] from lane ((2q+(w>>1))&3, p); f>=16: shp pair from owner.
__device__ __forceinline__ bf16x8 bfrag_cat(const unsigned (&g2nt)[2], const unsigned (&shp)[8],
                                            int srcP, int q, int p) {
  bf16x8 b;
  #pragma unroll
  for (int w = 0; w < 4; ++w) {
    int srcG = (((2 * q + (w >> 1)) & 3) << 4) + p;
    int vg = __shfl((int)g2nt[w & 1], srcG);
    int v2 = __shfl((int)shp[w],      srcP);
    int v3 = __shfl((int)shp[4 + w],  srcP);
    unsigned word = (q < 2) ? (unsigned)vg : ((q == 2) ? (unsigned)v2 : (unsigned)v3);
    b[2 * w]     = (short)(word & 0xFFFFu);
    b[2 * w + 1] = (short)(word >> 16);
  }
  return b;
}

// ---- generic 64->64 layer, A loaded from raw f32 weights (L2-hot) ----------
template<bool RELU>
__device__ __forceinline__ void layer64(const float* __restrict__ W, const float* __restrict__ bias,
                                        const unsigned (&uin)[4][4][2], unsigned (&uout)[4][4][2],
                                        int q, int p) {
  bf16x8 A[4][2];
  #pragma unroll
  for (int mt = 0; mt < 4; ++mt)
    #pragma unroll
    for (int kt = 0; kt < 2; ++kt)
      #pragma unroll
      for (int j = 0; j < 8; ++j)
        A[mt][kt][j] = (short)f2bf(W[(kt * 32 + 8 * q + j) * 64 + mt * 16 + p]);
  f32x4 bi[4];
  #pragma unroll
  for (int mt = 0; mt < 4; ++mt) bi[mt] = *(const f32x4*)(bias + mt * 16 + 4 * q);
  #pragma unroll
  for (int nt = 0; nt < 4; ++nt) {
    bf16x8 B0 = bfrag_u<0>(uin[nt], q, p);
    bf16x8 B1 = bfrag_u<1>(uin[nt], q, p);
    #pragma unroll
    for (int mt = 0; mt < 4; ++mt) {
      f32x4 acc = bi[mt];
      acc = mfma16(A[mt][0], B0, acc);
      acc = mfma16(A[mt][1], B1, acc);
      if (RELU) {
        acc.x = fmaxf(acc.x, 0.0f); acc.y = fmaxf(acc.y, 0.0f);
        acc.z = fmaxf(acc.z, 0.0f); acc.w = fmaxf(acc.w, 0.0f);
      }
      uout[nt][mt][0] = pk(acc.x, acc.y);
      uout[nt][mt][1] = pk(acc.z, acc.w);
    }
  }
}

__global__ __launch_bounds__(BLK)
void ngp_fused4(const float* __restrict__ pos,  const float* __restrict__ dirs,
                const float* __restrict__ emb,
                const float* __restrict__ gw0, const float* __restrict__ gb0,
                const float* __restrict__ gw1, const float* __restrict__ gb1,
                const float* __restrict__ dw,  const float* __restrict__ db,
                const float* __restrict__ cw0, const float* __restrict__ cb0,
                const float* __restrict__ cw1, const float* __restrict__ cb1,
                const float* __restrict__ cw2, const float* __restrict__ cb2,
                const float* __restrict__ rw,  const float* __restrict__ rb,
                float* __restrict__ outd, float* __restrict__ outrgb, int N)
{
  const int tid  = threadIdx.x;
  const int lane = tid & 63, wave = tid >> 6;
  const int q = lane >> 4, p = lane & 15;
  const int idx = blockIdx.x * BLK + tid;
  const int ic = min(idx, N - 1);
  const int ptb = blockIdx.x * BLK + wave * 64;

  const float pnx = pos[3 * ic + 0] * 0.5f;   // pn = positions / BOUND
  const float pny = pos[3 * ic + 1] * 0.5f;
  const float pnz = pos[3 * ic + 2] * 0.5f;

  // ---- hash encode: direct L2 gathers (tables are 512 KB, L2-resident) ----
  float enc[32];
  #pragma unroll
  for (int li = 0; li < 16; ++li) {
    const float2* tl = (const float2*)emb + li * TT;
    const int   res = 16 << li;
    const float rm1 = (float)(res - 1);
    float sx = (pnx + 1.0f) * 0.5f * rm1;
    float sy = (pny + 1.0f) * 0.5f * rm1;
    float sz = (pnz + 1.0f) * 0.5f * rm1;
    float fx = floorf(sx), fy = floorf(sy), fz = floorf(sz);
    float wx = sx - fx,    wy = sy - fy,    wz = sz - fz;
    int ix = (int)fx, iy = (int)fy, iz = (int)fz;
    int x0 = min(max(ix, 0),     res - 1), x1 = min(max(ix + 1, 0), res - 1);
    int y0 = min(max(iy, 0),     res - 1), y1 = min(max(iy + 1, 0), res - 1);
    int z0 = min(max(iz, 0),     res - 1), z1 = min(max(iz + 1, 0), res - 1);
    unsigned a0 = (unsigned)x0,         a1 = (unsigned)x1;
    unsigned b0 = (unsigned)y0 * 2481u, b1 = (unsigned)y1 * 2481u;
    unsigned d0 = (unsigned)z0 * 1941u, d1 = (unsigned)z1 * 1941u;
    float2 f0 = tl[(a0 ^ b0 ^ d0) & 4095u];
    float2 f1 = tl[(a0 ^ b0 ^ d1) & 4095u];
    float2 f2 = tl[(a0 ^ b1 ^ d0) & 4095u];
    float2 f3 = tl[(a0 ^ b1 ^ d1) & 4095u];
    float2 f4 = tl[(a1 ^ b0 ^ d0) & 4095u];
    float2 f5 = tl[(a1 ^ b0 ^ d1) & 4095u];
    float2 f6 = tl[(a1 ^ b1 ^ d0) & 4095u];
    float2 f7 = tl[(a1 ^ b1 ^ d1) & 4095u];
    // replicate reference's literal blend axis order (wx on dz-pairs)
    float omx = 1.0f - wx, omy = 1.0f - wy, omz = 1.0f - wz;
    float c00x = f0.x * omx + f1.x * wx, c00y = f0.y * omx + f1.y * wx;
    float c01x = f2.x * omx + f3.x * wx, c01y = f2.y * omx + f3.y * wx;
    float c10x = f4.x * omx + f5.x * wx, c10y = f4.y * omx + f5.y * wx;
    float c11x = f6.x * omx + f7.x * wx, c11y = f6.y * omx + f7.y * wx;
    float e0x = c00x * omy + c01x * wy,  e0y = c00y * omy + c01y * wy;
    float e1x = c10x * omy + c11x * wy,  e1y = c10y * omy + c11y * wy;
    enc[2 * li + 0] = e0x * omz + e1x * wz;
    enc[2 * li + 1] = e0y * omz + e1y * wz;
  }
  unsigned encp[16];
  #pragma unroll
  for (int m = 0; m < 16; ++m) encp[m] = pk(enc[2 * m], enc[2 * m + 1]);

  // ---- SH16 of own direction, packed to 8 words ---------------------------
  unsigned shp[8];
  {
    float ddx = dirs[3 * ic + 0], ddy = dirs[3 * ic + 1], ddz = dirs[3 * ic + 2];
    float nrm = fmaxf(sqrtf(ddx * ddx + ddy * ddy + ddz * ddz), 1e-12f);
    float x = ddx / nrm, y = ddy / nrm, z = ddz / nrm;
    float xx = x * x, yy = y * y, zz = z * z;
    float xy = x * y, yz = y * z, xz = x * z;
    float sh0  = 0.28209479177387814f;
    float sh1  = -0.48860251190291987f * y;
    float sh2  =  0.48860251190291987f * z;
    float sh3  = -0.48860251190291987f * x;
    float sh4  =  1.0925484305920792f * xy;
    float sh5  = -1.0925484305920792f * yz;
    float sh6  =  0.31539156525252005f * (2.0f * zz - xx - yy);
    float sh7  = -1.0925484305920792f * xz;
    float sh8  =  0.5462742152960396f * (xx - yy);
    float sh9  = -0.5900435899266435f * y * (3.0f * xx - yy);
    float sh10 =  2.890611442640554f * xy * z;
    float sh11 = -0.4570457994644658f * y * (4.0f * zz - xx - yy);
    float sh12 =  0.3731763325901154f * z * (2.0f * zz - 3.0f * xx - 3.0f * yy);
    float sh13 = -0.4570457994644658f * x * (4.0f * zz - xx - yy);
    float sh14 =  1.445305721320277f * z * (xx - yy);
    float sh15 = -0.5900435899266435f * x * (xx - 3.0f * yy);
    shp[0] = pk(sh0,  sh1);  shp[1] = pk(sh2,  sh3);
    shp[2] = pk(sh4,  sh5);  shp[3] = pk(sh6,  sh7);
    shp[4] = pk(sh8,  sh9);  shp[5] = pk(sh10, sh11);
    shp[6] = pk(sh12, sh13); shp[7] = pk(sh14, sh15);
  }

  unsigned uA[4][4][2], uB[4][4][2];

  { // L0: enc(32) -> 64, relu.  A from gw0 (32x64).
    bf16x8 A[4];
    #pragma unroll
    for (int mt = 0; mt < 4; ++mt)
      #pragma unroll
      for (int j = 0; j < 8; ++j)
        A[mt][j] = (short)f2bf(gw0[(8 * q + j) * 64 + mt * 16 + p]);
    f32x4 bi[4];
    #pragma unroll
    for (int mt = 0; mt < 4; ++mt) bi[mt] = *(const f32x4*)(gb0 + mt * 16 + 4 * q);
    #pragma unroll
    for (int nt = 0; nt < 4; ++nt) {
      bf16x8 B = bfrag_pt(encp, nt * 16 + p, q);
      #pragma unroll
      for (int mt = 0; mt < 4; ++mt) {
        f32x4 acc = mfma16(A[mt], B, bi[mt]);
        acc.x = fmaxf(acc.x, 0.0f); acc.y = fmaxf(acc.y, 0.0f);
        acc.z = fmaxf(acc.z, 0.0f); acc.w = fmaxf(acc.w, 0.0f);
        uA[nt][mt][0] = pk(acc.x, acc.y);
        uA[nt][mt][1] = pk(acc.z, acc.w);
      }
    }
  }

  layer64<true>(gw1, gb1, uA, uB, q, p);        // L1: 64->64, relu

  unsigned g2[4][2];
  { // L2: 64 -> 16 (dw, 64x16), no relu; density out; pack g pairs.
    bf16x8 A[2];
    #pragma unroll
    for (int kt = 0; kt < 2; ++kt)
      #pragma unroll
      for (int j = 0; j < 8; ++j)
        A[kt][j] = (short)f2bf(dw[(kt * 32 + 8 * q + j) * 16 + p]);
    f32x4 bi = *(const f32x4*)(db + 4 * q);
    #pragma unroll
    for (int nt = 0; nt < 4; ++nt) {
      bf16x8 B0 = bfrag_u<0>(uB[nt], q, p);
      bf16x8 B1 = bfrag_u<1>(uB[nt], q, p);
      f32x4 acc = mfma16(A[0], B0, bi);
      acc = mfma16(A[1], B1, acc);
      if (q == 0) {                 // g[0] = row 0 -> lane (0,p), acc.x
        int pt = ptb + nt * 16 + p;
        if (pt < N) outd[pt] = expf(acc.x - 1.0f);
      }
      g2[nt][0] = pk(acc.x, acc.y);
      g2[nt][1] = pk(acc.z, acc.w);
    }
  }

  { // L3: concat(g[1:16], sh16) (32) -> 64, relu. A from cw0 (31x64), k-shifted
    // (k=0 row zeroed so g[0]'s slot is dead).
    bf16x8 A[4];
    #pragma unroll
    for (int mt = 0; mt < 4; ++mt)
      #pragma unroll
      for (int j = 0; j < 8; ++j) {
        int k = 8 * q + j;
        float v = (k == 0) ? 0.0f : cw0[(k - 1) * 64 + mt * 16 + p];
        A[mt][j] = (short)f2bf(v);
      }
    f32x4 bi[4];
    #pragma unroll
    for (int mt = 0; mt < 4; ++mt) bi[mt] = *(const f32x4*)(cb0 + mt * 16 + 4 * q);
    #pragma unroll
    for (int nt = 0; nt < 4; ++nt) {
      bf16x8 B = bfrag_cat(g2[nt], shp, nt * 16 + p, q, p);
      #pragma unroll
      for (int mt = 0; mt < 4; ++mt) {
        f32x4 acc = mfma16(A[mt], B, bi[mt]);
        acc.x = fmaxf(acc.x, 0.0f); acc.y = fmaxf(acc.y, 0.0f);
        acc.z = fmaxf(acc.z, 0.0f); acc.w = fmaxf(acc.w, 0.0f);
        uA[nt][mt][0] = pk(acc.x, acc.y);
        uA[nt][mt][1] = pk(acc.z, acc.w);
      }
    }
  }

  layer64<false>(cw1, cb1, uA, uB, q, p);       // L4: 64->64
  layer64<false>(cw2, cb2, uB, uA, q, p);       // L5: 64->64

  { // L6: 64 -> 3 (rw, 64x3), sigmoid out. A rows >=3 zeroed.
    bf16x8 A[2];
    #pragma unroll
    for (int kt = 0; kt < 2; ++kt)
      #pragma unroll
      for (int j = 0; j < 8; ++j) {
        int k = kt * 32 + 8 * q + j;
        float v = (p < 3) ? rw[k * 3 + p] : 0.0f;
        A[kt][j] = (short)f2bf(v);
      }
    float r0 = rb[0], r1 = rb[1], r2 = rb[2];
    #pragma unroll
    for (int nt = 0; nt < 4; ++nt) {
      bf16x8 B0 = bfrag_u<0>(uA[nt], q, p);
      bf16x8 B1 = bfrag_u<1>(uA[nt], q, p);
      f32x4 acc;
      acc.x = (q == 0) ? r0 : 0.0f;
      acc.y = (q == 0) ? r1 : 0.0f;
      acc.z = (q == 0) ? r2 : 0.0f;
      acc.w = 0.0f;
      acc = mfma16(A[0], B0, acc);
      acc = mfma16(A[1], B1, acc);
      if (q == 0) {                 // rgb = rows 0..2 -> lane (0,p): acc.x/y/z
        int pt = ptb + nt * 16 + p;
        if (pt < N) {
          outrgb[3 * pt + 0] = 1.0f / (1.0f + expf(-acc.x));
          outrgb[3 * pt + 1] = 1.0f / (1.0f + expf(-acc.y));
          outrgb[3 * pt + 2] = 1.0f / (1.0f + expf(-acc.z));
        }
      }
    }
  }
}

extern "C" void kernel_launch(void* const* d_in, const int* in_sizes, int n_in,
                              void* d_out, int out_size, void* d_ws, size_t ws_size,
                              hipStream_t stream) {
  const float* pos  = (const float*)d_in[0];
  const float* dirs = (const float*)d_in[1];
  const float* emb  = (const float*)d_in[2];
  const float* gw0  = (const float*)d_in[3];
  const float* gb0  = (const float*)d_in[4];
  const float* gw1  = (const float*)d_in[5];
  const float* gb1  = (const float*)d_in[6];
  const float* dw   = (const float*)d_in[7];
  const float* db   = (const float*)d_in[8];
  const float* cw0  = (const float*)d_in[9];
  const float* cb0  = (const float*)d_in[10];
  const float* cw1  = (const float*)d_in[11];
  const float* cb1  = (const float*)d_in[12];
  const float* cw2  = (const float*)d_in[13];
  const float* cb2  = (const float*)d_in[14];
  const float* rw   = (const float*)d_in[15];
  const float* rb   = (const float*)d_in[16];

  const int N = in_sizes[0] / 3;
  float* outd   = (float*)d_out;
  float* outrgb = outd + N;

  const int grid = (N + BLK - 1) / BLK;
  hipLaunchKernelGGL(ngp_fused4, dim3(grid), dim3(BLK), 0, stream,
                     pos, dirs, emb, gw0, gb0, gw1, gb1, dw, db,
                     cw0, cb0, cw1, cb1, cw2, cb2, rw, rb,
                     outd, outrgb, N);
}

// Round 10
// 262.875 us; speedup vs baseline: 2.6385x; 1.6008x over previous
//
#include <hip/hip_runtime.h>
#include <math.h>

#define BLK 256
#define TT  4096   // T0 = min(16^3, 2^19) = 4096 for every level

typedef short bf16x8 __attribute__((ext_vector_type(8)));
typedef float f32x4  __attribute__((ext_vector_type(4)));

__device__ __forceinline__ unsigned short f2bf(float f) {
  unsigned u = __builtin_bit_cast(unsigned, f);
  return (unsigned short)((u + 0x7FFFu + ((u >> 16) & 1u)) >> 16);
}
__device__ __forceinline__ unsigned pk(float a, float b) {
  return (unsigned)f2bf(a) | ((unsigned)f2bf(b) << 16);
}
__device__ __forceinline__ float bflo(unsigned w) {   // low bf16 -> f32
  return __builtin_bit_cast(float, w << 16);
}
__device__ __forceinline__ float bfhi(unsigned w) {   // high bf16 -> f32
  return __builtin_bit_cast(float, w & 0xFFFF0000u);
}
__device__ __forceinline__ f32x4 mfma16(bf16x8 a, bf16x8 b, f32x4 c) {
  return __builtin_amdgcn_mfma_f32_16x16x32_bf16(a, b, c, 0, 0, 0);
}

// ---- B-fragment builders: pure cross-lane (no LDS) -------------------------
// MFMA frag conventions (m89-verified D; A/B k-permutation cancels when A and
// B use the same convention): lane (q,p): A[row=p][k=32kt+8q+j];
// B[k=32kt+8q+j][col=p]; D[row=4q+r][col=p].

__device__ __forceinline__ bf16x8 bfrag_pt(const unsigned (&ep)[16], int src, int q) {
  bf16x8 b;
  #pragma unroll
  for (int w = 0; w < 4; ++w) {
    int v0 = __shfl((int)ep[w],      src);
    int v1 = __shfl((int)ep[4 + w],  src);
    int v2 = __shfl((int)ep[8 + w],  src);
    int v3 = __shfl((int)ep[12 + w], src);
    int lo = (q & 1) ? v1 : v0;
    int hi = (q & 1) ? v3 : v2;
    unsigned word = (unsigned)((q & 2) ? hi : lo);
    b[2 * w]     = (short)(word & 0xFFFFu);
    b[2 * w + 1] = (short)(word >> 16);
  }
  return b;
}

template<int KT_>
__device__ __forceinline__ bf16x8 bfrag_u(const unsigned (&unt)[4][2], int q, int p) {
  bf16x8 b;
  #pragma unroll
  for (int w = 0; w < 4; ++w) {
    int src = (((2 * q + (w >> 1)) & 3) << 4) + p;
    int v0 = __shfl((int)unt[2 * KT_][w & 1],     src);
    int v1 = __shfl((int)unt[2 * KT_ + 1][w & 1], src);
    unsigned word = (unsigned)((q >> 1) ? v1 : v0);
    b[2 * w]     = (short)(word & 0xFFFFu);
    b[2 * w + 1] = (short)(word >> 16);
  }
  return b;
}

__device__ __forceinline__ bf16x8 bfrag_cat(const unsigned (&g2nt)[2], const unsigned (&shp)[8],
                                            int srcP, int q, int p) {
  bf16x8 b;
  #pragma unroll
  for (int w = 0; w < 4; ++w) {
    int srcG = (((2 * q + (w >> 1)) & 3) << 4) + p;
    int vg = __shfl((int)g2nt[w & 1], srcG);
    int v2 = __shfl((int)shp[w],      srcP);
    int v3 = __shfl((int)shp[4 + w],  srcP);
    unsigned word = (q < 2) ? (unsigned)vg : ((q == 2) ? (unsigned)v2 : (unsigned)v3);
    b[2 * w]     = (short)(word & 0xFFFFu);
    b[2 * w + 1] = (short)(word >> 16);
  }
  return b;
}

// ---- generic 64->64 layer, A loaded from raw f32 weights (L2-hot) ----------
template<bool RELU>
__device__ __forceinline__ void layer64(const float* __restrict__ W, const float* __restrict__ bias,
                                        const unsigned (&uin)[4][4][2], unsigned (&uout)[4][4][2],
                                        int q, int p) {
  bf16x8 A[4][2];
  #pragma unroll
  for (int mt = 0; mt < 4; ++mt)
    #pragma unroll
    for (int kt = 0; kt < 2; ++kt)
      #pragma unroll
      for (int j = 0; j < 8; ++j)
        A[mt][kt][j] = (short)f2bf(W[(kt * 32 + 8 * q + j) * 64 + mt * 16 + p]);
  f32x4 bi[4];
  #pragma unroll
  for (int mt = 0; mt < 4; ++mt) bi[mt] = *(const f32x4*)(bias + mt * 16 + 4 * q);
  #pragma unroll
  for (int nt = 0; nt < 4; ++nt) {
    bf16x8 B0 = bfrag_u<0>(uin[nt], q, p);
    bf16x8 B1 = bfrag_u<1>(uin[nt], q, p);
    #pragma unroll
    for (int mt = 0; mt < 4; ++mt) {
      f32x4 acc = bi[mt];
      acc = mfma16(A[mt][0], B0, acc);
      acc = mfma16(A[mt][1], B1, acc);
      if (RELU) {
        acc.x = fmaxf(acc.x, 0.0f); acc.y = fmaxf(acc.y, 0.0f);
        acc.z = fmaxf(acc.z, 0.0f); acc.w = fmaxf(acc.w, 0.0f);
      }
      uout[nt][mt][0] = pk(acc.x, acc.y);
      uout[nt][mt][1] = pk(acc.z, acc.w);
    }
  }
}

__global__ __launch_bounds__(BLK)
void ngp_fused5(const float* __restrict__ pos,  const float* __restrict__ dirs,
                const float* __restrict__ emb,
                const float* __restrict__ gw0, const float* __restrict__ gb0,
                const float* __restrict__ gw1, const float* __restrict__ gb1,
                const float* __restrict__ dw,  const float* __restrict__ db,
                const float* __restrict__ cw0, const float* __restrict__ cb0,
                const float* __restrict__ cw1, const float* __restrict__ cb1,
                const float* __restrict__ cw2, const float* __restrict__ cb2,
                const float* __restrict__ rw,  const float* __restrict__ rb,
                float* __restrict__ outd, float* __restrict__ outrgb, int N)
{
  // Double-buffered bf16 hash-table stage: 2 x 16 KB. One barrier per level;
  // stage(li+1) overlaps gather+blend(li). Gathers become single-dword
  // ds_read_b32 (2-4-way bank alias) instead of 64-way divergent L1 traffic.
  __shared__ unsigned tab[2][TT];

  const int tid  = threadIdx.x;
  const int lane = tid & 63, wave = tid >> 6;
  const int q = lane >> 4, p = lane & 15;
  const int idx = blockIdx.x * BLK + tid;
  const int ic = min(idx, N - 1);
  const int ptb = blockIdx.x * BLK + wave * 64;

  const float pnx = pos[3 * ic + 0] * 0.5f;   // pn = positions / BOUND
  const float pny = pos[3 * ic + 1] * 0.5f;
  const float pnz = pos[3 * ic + 2] * 0.5f;

  auto stage = [&](int li) {
    const f32x4* s4 = (const f32x4*)(emb + (size_t)li * (TT * 2));
    uint2* dst = (uint2*)tab[li & 1];
    #pragma unroll
    for (int j = 0; j < (TT / 2) / BLK; ++j) {        // 8 iters: 2048 uint2
      f32x4 v = s4[tid + j * BLK];
      uint2 w; w.x = pk(v.x, v.y); w.y = pk(v.z, v.w);
      dst[tid + j * BLK] = w;
    }
  };

  float enc[32];
  stage(0);
  __syncthreads();
  #pragma unroll
  for (int li = 0; li < 16; ++li) {
    if (li < 15) stage(li + 1);                        // write OTHER buffer
    const unsigned* t = tab[li & 1];
    const int   res = 16 << li;
    const float rm1 = (float)(res - 1);
    float sx = (pnx + 1.0f) * 0.5f * rm1;
    float sy = (pny + 1.0f) * 0.5f * rm1;
    float sz = (pnz + 1.0f) * 0.5f * rm1;
    float fx = floorf(sx), fy = floorf(sy), fz = floorf(sz);
    float wx = sx - fx,    wy = sy - fy,    wz = sz - fz;
    int ix = (int)fx, iy = (int)fy, iz = (int)fz;
    int x0 = min(max(ix, 0),     res - 1), x1 = min(max(ix + 1, 0), res - 1);
    int y0 = min(max(iy, 0),     res - 1), y1 = min(max(iy + 1, 0), res - 1);
    int z0 = min(max(iz, 0),     res - 1), z1 = min(max(iz + 1, 0), res - 1);
    unsigned a0 = (unsigned)x0,         a1 = (unsigned)x1;
    unsigned b0 = (unsigned)y0 * 2481u, b1 = (unsigned)y1 * 2481u;
    unsigned d0 = (unsigned)z0 * 1941u, d1 = (unsigned)z1 * 1941u;
    unsigned w0 = t[(a0 ^ b0 ^ d0) & 4095u];
    unsigned w1 = t[(a0 ^ b0 ^ d1) & 4095u];
    unsigned w2 = t[(a0 ^ b1 ^ d0) & 4095u];
    unsigned w3 = t[(a0 ^ b1 ^ d1) & 4095u];
    unsigned w4 = t[(a1 ^ b0 ^ d0) & 4095u];
    unsigned w5 = t[(a1 ^ b0 ^ d1) & 4095u];
    unsigned w6 = t[(a1 ^ b1 ^ d0) & 4095u];
    unsigned w7 = t[(a1 ^ b1 ^ d1) & 4095u];
    // replicate reference's literal blend axis order (wx on dz-pairs)
    float omx = 1.0f - wx, omy = 1.0f - wy, omz = 1.0f - wz;
    float c00x = bflo(w0) * omx + bflo(w1) * wx, c00y = bfhi(w0) * omx + bfhi(w1) * wx;
    float c01x = bflo(w2) * omx + bflo(w3) * wx, c01y = bfhi(w2) * omx + bfhi(w3) * wx;
    float c10x = bflo(w4) * omx + bflo(w5) * wx, c10y = bfhi(w4) * omx + bfhi(w5) * wx;
    float c11x = bflo(w6) * omx + bflo(w7) * wx, c11y = bfhi(w6) * omx + bfhi(w7) * wx;
    float e0x = c00x * omy + c01x * wy,  e0y = c00y * omy + c01y * wy;
    float e1x = c10x * omy + c11x * wy,  e1y = c10y * omy + c11y * wy;
    enc[2 * li + 0] = e0x * omz + e1x * wz;
    enc[2 * li + 1] = e0y * omz + e1y * wz;
    __syncthreads();   // gathers(li) done; stage(li+1) complete for next iter
  }
  unsigned encp[16];
  #pragma unroll
  for (int m = 0; m < 16; ++m) encp[m] = pk(enc[2 * m], enc[2 * m + 1]);

  // ---- SH16 of own direction, packed to 8 words ---------------------------
  unsigned shp[8];
  {
    float ddx = dirs[3 * ic + 0], ddy = dirs[3 * ic + 1], ddz = dirs[3 * ic + 2];
    float nrm = fmaxf(sqrtf(ddx * ddx + ddy * ddy + ddz * ddz), 1e-12f);
    float x = ddx / nrm, y = ddy / nrm, z = ddz / nrm;
    float xx = x * x, yy = y * y, zz = z * z;
    float xy = x * y, yz = y * z, xz = x * z;
    float sh0  = 0.28209479177387814f;
    float sh1  = -0.48860251190291987f * y;
    float sh2  =  0.48860251190291987f * z;
    float sh3  = -0.48860251190291987f * x;
    float sh4  =  1.0925484305920792f * xy;
    float sh5  = -1.0925484305920792f * yz;
    float sh6  =  0.31539156525252005f * (2.0f * zz - xx - yy);
    float sh7  = -1.0925484305920792f * xz;
    float sh8  =  0.5462742152960396f * (xx - yy);
    float sh9  = -0.5900435899266435f * y * (3.0f * xx - yy);
    float sh10 =  2.890611442640554f * xy * z;
    float sh11 = -0.4570457994644658f * y * (4.0f * zz - xx - yy);
    float sh12 =  0.3731763325901154f * z * (2.0f * zz - 3.0f * xx - 3.0f * yy);
    float sh13 = -0.4570457994644658f * x * (4.0f * zz - xx - yy);
    float sh14 =  1.445305721320277f * z * (xx - yy);
    float sh15 = -0.5900435899266435f * x * (xx - 3.0f * yy);
    shp[0] = pk(sh0,  sh1);  shp[1] = pk(sh2,  sh3);
    shp[2] = pk(sh4,  sh5);  shp[3] = pk(sh6,  sh7);
    shp[4] = pk(sh8,  sh9);  shp[5] = pk(sh10, sh11);
    shp[6] = pk(sh12, sh13); shp[7] = pk(sh14, sh15);
  }

  unsigned uA[4][4][2], uB[4][4][2];

  { // L0: enc(32) -> 64, relu.  A from gw0 (32x64).
    bf16x8 A[4];
    #pragma unroll
    for (int mt = 0; mt < 4; ++mt)
      #pragma unroll
      for (int j = 0; j < 8; ++j)
        A[mt][j] = (short)f2bf(gw0[(8 * q + j) * 64 + mt * 16 + p]);
    f32x4 bi[4];
    #pragma unroll
    for (int mt = 0; mt < 4; ++mt) bi[mt] = *(const f32x4*)(gb0 + mt * 16 + 4 * q);
    #pragma unroll
    for (int nt = 0; nt < 4; ++nt) {
      bf16x8 B = bfrag_pt(encp, nt * 16 + p, q);
      #pragma unroll
      for (int mt = 0; mt < 4; ++mt) {
        f32x4 acc = mfma16(A[mt], B, bi[mt]);
        acc.x = fmaxf(acc.x, 0.0f); acc.y = fmaxf(acc.y, 0.0f);
        acc.z = fmaxf(acc.z, 0.0f); acc.w = fmaxf(acc.w, 0.0f);
        uA[nt][mt][0] = pk(acc.x, acc.y);
        uA[nt][mt][1] = pk(acc.z, acc.w);
      }
    }
  }

  layer64<true>(gw1, gb1, uA, uB, q, p);        // L1: 64->64, relu

  unsigned g2[4][2];
  { // L2: 64 -> 16 (dw, 64x16), no relu; density out; pack g pairs.
    bf16x8 A[2];
    #pragma unroll
    for (int kt = 0; kt < 2; ++kt)
      #pragma unroll
      for (int j = 0; j < 8; ++j)
        A[kt][j] = (short)f2bf(dw[(kt * 32 + 8 * q + j) * 16 + p]);
    f32x4 bi = *(const f32x4*)(db + 4 * q);
    #pragma unroll
    for (int nt = 0; nt < 4; ++nt) {
      bf16x8 B0 = bfrag_u<0>(uB[nt], q, p);
      bf16x8 B1 = bfrag_u<1>(uB[nt], q, p);
      f32x4 acc = mfma16(A[0], B0, bi);
      acc = mfma16(A[1], B1, acc);
      if (q == 0) {                 // g[0] = row 0 -> lane (0,p), acc.x
        int pt = ptb + nt * 16 + p;
        if (pt < N) outd[pt] = expf(acc.x - 1.0f);
      }
      g2[nt][0] = pk(acc.x, acc.y);
      g2[nt][1] = pk(acc.z, acc.w);
    }
  }

  { // L3: concat(g[1:16], sh16) (32) -> 64, relu. A from cw0 (31x64), k-shifted
    bf16x8 A[4];
    #pragma unroll
    for (int mt = 0; mt < 4; ++mt)
      #pragma unroll
      for (int j = 0; j < 8; ++j) {
        int k = 8 * q + j;
        float v = (k == 0) ? 0.0f : cw0[(k - 1) * 64 + mt * 16 + p];
        A[mt][j] = (short)f2bf(v);
      }
    f32x4 bi[4];
    #pragma unroll
    for (int mt = 0; mt < 4; ++mt) bi[mt] = *(const f32x4*)(cb0 + mt * 16 + 4 * q);
    #pragma unroll
    for (int nt = 0; nt < 4; ++nt) {
      bf16x8 B = bfrag_cat(g2[nt], shp, nt * 16 + p, q, p);
      #pragma unroll
      for (int mt = 0; mt < 4; ++mt) {
        f32x4 acc = mfma16(A[mt], B, bi[mt]);
        acc.x = fmaxf(acc.x, 0.0f); acc.y = fmaxf(acc.y, 0.0f);
        acc.z = fmaxf(acc.z, 0.0f); acc.w = fmaxf(acc.w, 0.0f);
        uA[nt][mt][0] = pk(acc.x, acc.y);
        uA[nt][mt][1] = pk(acc.z, acc.w);
      }
    }
  }

  layer64<false>(cw1, cb1, uA, uB, q, p);       // L4: 64->64
  layer64<false>(cw2, cb2, uB, uA, q, p);       // L5: 64->64

  { // L6: 64 -> 3 (rw, 64x3), sigmoid out. A rows >=3 zeroed.
    bf16x8 A[2];
    #pragma unroll
    for (int kt = 0; kt < 2; ++kt)
      #pragma unroll
      for (int j = 0; j < 8; ++j) {
        int k = kt * 32 + 8 * q + j;
        float v = (p < 3) ? rw[k * 3 + p] : 0.0f;
        A[kt][j] = (short)f2bf(v);
      }
    float r0 = rb[0], r1 = rb[1], r2 = rb[2];
    #pragma unroll
    for (int nt = 0; nt < 4; ++nt) {
      bf16x8 B0 = bfrag_u<0>(uA[nt], q, p);
      bf16x8 B1 = bfrag_u<1>(uA[nt], q, p);
      f32x4 acc;
      acc.x = (q == 0) ? r0 : 0.0f;
      acc.y = (q == 0) ? r1 : 0.0f;
      acc.z = (q == 0) ? r2 : 0.0f;
      acc.w = 0.0f;
      acc = mfma16(A[0], B0, acc);
      acc = mfma16(A[1], B1, acc);
      if (q == 0) {                 // rgb = rows 0..2 -> lane (0,p): acc.x/y/z
        int pt = ptb + nt * 16 + p;
        if (pt < N) {
          outrgb[3 * pt + 0] = 1.0f / (1.0f + expf(-acc.x));
          outrgb[3 * pt + 1] = 1.0f / (1.0f + expf(-acc.y));
          outrgb[3 * pt + 2] = 1.0f / (1.0f + expf(-acc.z));
        }
      }
    }
  }
}

extern "C" void kernel_launch(void* const* d_in, const int* in_sizes, int n_in,
                              void* d_out, int out_size, void* d_ws, size_t ws_size,
                              hipStream_t stream) {
  const float* pos  = (const float*)d_in[0];
  const float* dirs = (const float*)d_in[1];
  const float* emb  = (const float*)d_in[2];
  const float* gw0  = (const float*)d_in[3];
  const float* gb0  = (const float*)d_in[4];
  const float* gw1  = (const float*)d_in[5];
  const float* gb1  = (const float*)d_in[6];
  const float* dw   = (const float*)d_in[7];
  const float* db   = (const float*)d_in[8];
  const float* cw0  = (const float*)d_in[9];
  const float* cb0  = (const float*)d_in[10];
  const float* cw1  = (const float*)d_in[11];
  const float* cb1  = (const float*)d_in[12];
  const float* cw2  = (const float*)d_in[13];
  const float* cb2  = (const float*)d_in[14];
  const float* rw   = (const float*)d_in[15];
  const float* rb   = (const float*)d_in[16];

  const int N = in_sizes[0] / 3;
  float* outd   = (float*)d_out;
  float* outrgb = outd + N;

  const int grid = (N + BLK - 1) / BLK;
  hipLaunchKernelGGL(ngp_fused5, dim3(grid), dim3(BLK), 0, stream,
                     pos, dirs, emb, gw0, gb0, gw1, gb1, dw, db,
                     cw0, cb0, cw1, cb1, cw2, cb2, rw, rb,
                     outd, outrgb, N);
}